// Round 10
// baseline (252.143 us; speedup 1.0000x reference)
//
#include <hip/hip_runtime.h>
#include <hip/hip_bf16.h>

// MHA: B=2, S=2048, D=1024, H=16, HD=64. fp32 in, fp32 out.
// Swizzled bf16 inter-kernel layouts (16B blocks) so all staging is contiguous DMA:
//   A/W swizzle ([R][K=1024]): block g=((r>>7)*128+(k>>3))*128+(r&127)
//   K_sw/V_sw: block g=((bh*32+kt)*8+kc)*64+row
// ws: [0,8)MB Qb [B,H,S,HD] | [8,16) K_sw | [16,24) V_sw | [24,32) Wqt/Wkt/Wvt (2MB each)
//     ctx_sw overlays [24,32) after QKV GEMM; Wot overlays [0,2) after fattn.
// Q-proj scale folds 1/sqrt(HD)*log2(e) so fattn uses native exp2.
// R9->R10: fattn restructured 8x16 -> 4x32 rows/wave (halves redundant LDS b-frag
// reads); row-sums via MFMA-with-ones (kills per-element VALU adds + shfl);
// packed bf16 cvt (R7==R8 proved __float22bfloat162_rn bit-exact vs explicit pack).

typedef short s16x8 __attribute__((ext_vector_type(8)));
typedef float f32x4v __attribute__((ext_vector_type(4)));

__device__ inline unsigned short f2bf(float f) {   // RNE
    union { float f; unsigned int i; } x; x.f = f;
    unsigned int r = x.i + 0x7FFFu + ((x.i >> 16) & 1u);
    return (unsigned short)(r >> 16);
}
__device__ inline unsigned int pkbf(float lo, float hi) {  // packed RNE: lo16=bf(lo)
    union { __hip_bfloat162 v; unsigned int u; } x;
    x.v = __float22bfloat162_rn(make_float2(lo, hi));
    return x.u;
}

// async global->LDS, 16B/lane. Global address PER-LANE; LDS base wave-uniform,
// HW writes base + lane*16.
__device__ inline void gld_lds16(const unsigned short* g, unsigned short* l) {
    __builtin_amdgcn_global_load_lds(
        (const __attribute__((address_space(1))) unsigned int*)(const void*)g,
        (__attribute__((address_space(3))) unsigned int*)(void*)l,
        16, 0, 0);
}

// W[K=1024][N=1024] fp32 -> Wt bf16 in A/W swizzle (transpose+convert). z selects tensor.
__global__ __launch_bounds__(256)
void cvt3(const float* __restrict__ W0, const float* __restrict__ W1, const float* __restrict__ W2,
          unsigned short* __restrict__ T0, unsigned short* __restrict__ T1, unsigned short* __restrict__ T2) {
    const float* W = (blockIdx.z == 0) ? W0 : (blockIdx.z == 1) ? W1 : W2;
    unsigned short* Wt = (blockIdx.z == 0) ? T0 : (blockIdx.z == 1) ? T1 : T2;
    __shared__ __align__(16) unsigned short Ls[64 * 72];
    const int t = threadIdx.x;
    const int k0 = blockIdx.y * 64, n0 = blockIdx.x * 64;
    const int r = t >> 4, c4 = (t & 15) * 4;
    #pragma unroll
    for (int i = 0; i < 4; ++i) {
        float4 wv = *(const float4*)&W[(size_t)(k0 + r + i * 16) * 1024 + n0 + c4];
        Ls[(c4 + 0) * 72 + r + i * 16] = f2bf(wv.x);
        Ls[(c4 + 1) * 72 + r + i * 16] = f2bf(wv.y);
        Ls[(c4 + 2) * 72 + r + i * 16] = f2bf(wv.z);
        Ls[(c4 + 3) * 72 + r + i * 16] = f2bf(wv.w);
    }
    __syncthreads();
    #pragma unroll
    for (int i = 0; i < 2; ++i) {
        const int p = i * 256 + t;
        const int n = p & 63, kc = p >> 6;
        s16x8 v = *(const s16x8*)&Ls[n * 72 + kc * 8];
        const int gn = n0 + n, k = k0 + kc * 8;
        const size_t g = ((size_t)(gn >> 7) * 128 + (k >> 3)) * 128 + (gn & 127);
        *(s16x8*)&Wt[g * 8] = v;
    }
}

// Fused QKV GEMM: C = X @ W^T per z in {Q,K,V}. 128x128 tile, BK=64.
// Grid (8, 32, 3) = 768 blocks -> 3 blocks/CU.
__global__ __launch_bounds__(256, 3)
void gemm_qkv(const float* __restrict__ A0, const float* __restrict__ A1, const float* __restrict__ A2,
              const unsigned short* __restrict__ W0, const unsigned short* __restrict__ W1,
              const unsigned short* __restrict__ W2,
              unsigned short* __restrict__ OQ, unsigned short* __restrict__ OK,
              unsigned short* __restrict__ OV, float scaleQ) {
    const int z = blockIdx.z;
    const float* Av = (z == 0) ? A0 : (z == 1) ? A1 : A2;
    const unsigned short* Bsw = (z == 0) ? W0 : (z == 1) ? W1 : W2;
    const float scale = (z == 0) ? scaleQ : 1.0f;

    __shared__ __align__(16) unsigned short Al[1024 * 8];
    __shared__ __align__(16) unsigned short Bl[1024 * 8];
    const int t = threadIdx.x;
    const int lane = t & 63, w = t >> 6;
    const int ln = lane & 15, qd = lane >> 4;
    const int mw = (w & 1) * 64, nw = (w >> 1) * 64;
    const int m0 = blockIdx.y * 128, n0 = blockIdx.x * 128;

    f32x4v acc[4][4] = {};

    for (int k0 = 0; k0 < 1024; k0 += 64) {
        __syncthreads();
        {   // B: contiguous DMA (per-lane address via t)
            const size_t gb = ((size_t)(n0 >> 7) * 128 + (k0 >> 3)) * 128;
            #pragma unroll
            for (int j = 0; j < 4; ++j)
                gld_lds16(Bsw + (gb + j * 256 + t) * 8, &Bl[(j * 256 + w * 64) * 8]);
        }
        #pragma unroll
        for (int j = 0; j < 4; ++j) {       // A: fp32 -> bf16, packed cvt
            const int p = j * 256 + t;
            const int row = p >> 3, kc = p & 7;
            const float* src = Av + (size_t)(m0 + row) * 1024 + k0 + kc * 8;
            float4 f0 = ((const float4*)src)[0];
            float4 f1 = ((const float4*)src)[1];
            uint4 u;
            u.x = pkbf(f0.x, f0.y); u.y = pkbf(f0.z, f0.w);
            u.z = pkbf(f1.x, f1.y); u.w = pkbf(f1.z, f1.w);
            *(uint4*)&Al[(kc * 128 + (row ^ kc)) * 8] = u;
        }
        __syncthreads();

        #pragma unroll
        for (int kk = 0; kk < 2; ++kk) {
            const int kc = kk * 4 + qd;
            s16x8 a[4], b[4];
            #pragma unroll
            for (int mt = 0; mt < 4; ++mt)
                a[mt] = *(const s16x8*)&Al[(kc * 128 + ((mw + mt * 16 + ln) ^ kc)) * 8];
            #pragma unroll
            for (int nt = 0; nt < 4; ++nt)
                b[nt] = *(const s16x8*)&Bl[(kc * 128 + nw + nt * 16 + ln) * 8];
            #pragma unroll
            for (int mt = 0; mt < 4; ++mt)
                #pragma unroll
                for (int nt = 0; nt < 4; ++nt)
                    acc[mt][nt] = __builtin_amdgcn_mfma_f32_16x16x32_bf16(a[mt], b[nt], acc[mt][nt], 0, 0, 0);
        }
    }

    #pragma unroll
    for (int mt = 0; mt < 4; ++mt)
        #pragma unroll
        for (int nt = 0; nt < 4; ++nt) {
            if (z == 2) {
                // V_sw: the 4 i-values are consecutive s -> one ushort4 store
                const int m = m0 + mw + mt * 16 + qd * 4;   // i=0
                const int n = n0 + nw + nt * 16 + ln;
                const int bh = (m >> 11) * 16 + (n >> 6), s = m & 2047, hd = n & 63;
                const size_t g = ((size_t)(bh * 32 + (s >> 6)) * 8 + ((s >> 3) & 7)) * 64 + hd;
                unsigned int lo = pkbf(acc[mt][nt][0], acc[mt][nt][1]);
                unsigned int hi = pkbf(acc[mt][nt][2], acc[mt][nt][3]);
                uint2 u2 = make_uint2(lo, hi);
                *(uint2*)&OV[g * 8 + (s & 7)] = u2;
            } else {
                #pragma unroll
                for (int i = 0; i < 4; ++i) {
                    const int m = m0 + mw + mt * 16 + qd * 4 + i;
                    const int n = n0 + nw + nt * 16 + ln;
                    const float v = acc[mt][nt][i] * scale;
                    const int bh = (m >> 11) * 16 + (n >> 6), s = m & 2047, hd = n & 63;
                    if (z == 0) {
                        OQ[((size_t)bh * 2048 + s) * 64 + hd] = f2bf(v);
                    } else {
                        const size_t g = ((size_t)(bh * 32 + (s >> 6)) * 8 + (hd >> 3)) * 64 + (s & 63);
                        OK[g * 8 + (hd & 7)] = f2bf(v);
                    }
                }
            }
        }
}

// Output GEMM: out[M=4096][N=1024] fp32 = ctx_sw @ Wot^T. 128x64 tile, BK=64.
// Grid (16, 32) = 512 blocks -> 2 blocks/CU. Wave tile 64x32.
__global__ __launch_bounds__(256, 2)
void gemm_out(const unsigned short* __restrict__ Asw, const unsigned short* __restrict__ Bsw,
              float* __restrict__ outF) {
    __shared__ __align__(16) unsigned short Al[1024 * 8];
    __shared__ __align__(16) unsigned short Bl[512 * 8];
    const int t = threadIdx.x;
    const int lane = t & 63, w = t >> 6;
    const int ln = lane & 15, qd = lane >> 4;
    const int mw = (w & 1) * 64, nw = (w >> 1) * 32;
    const int m0 = blockIdx.y * 128, n0 = blockIdx.x * 64;

    f32x4v acc[4][2] = {};

    for (int k0 = 0; k0 < 1024; k0 += 64) {
        __syncthreads();
        {   // A: 1024 contiguous blocks (per-lane address via t)
            const size_t ga = ((size_t)(m0 >> 7) * 128 + (k0 >> 3)) * 128;
            #pragma unroll
            for (int j = 0; j < 4; ++j)
                gld_lds16(Asw + (ga + j * 256 + t) * 8, &Al[(j * 256 + w * 64) * 8]);
        }
        {   // B: per-lane address (+ lane)
            #pragma unroll
            for (int i = 0; i < 2; ++i) {
                const int c = w * 2 + i;
                const size_t gb = ((size_t)(n0 >> 7) * 128 + (k0 >> 3) + c) * 128 + (n0 & 127) + lane;
                gld_lds16(Bsw + gb * 8, &Bl[(c * 64) * 8]);
            }
        }
        __syncthreads();

        #pragma unroll
        for (int kk = 0; kk < 2; ++kk) {
            const int kc = kk * 4 + qd;
            s16x8 a[4], b[2];
            #pragma unroll
            for (int mt = 0; mt < 4; ++mt)
                a[mt] = *(const s16x8*)&Al[(kc * 128 + mw + mt * 16 + ln) * 8];
            #pragma unroll
            for (int nt = 0; nt < 2; ++nt)
                b[nt] = *(const s16x8*)&Bl[(kc * 64 + nw + nt * 16 + ln) * 8];
            #pragma unroll
            for (int mt = 0; mt < 4; ++mt)
                #pragma unroll
                for (int nt = 0; nt < 2; ++nt)
                    acc[mt][nt] = __builtin_amdgcn_mfma_f32_16x16x32_bf16(a[mt], b[nt], acc[mt][nt], 0, 0, 0);
        }
    }

    #pragma unroll
    for (int mt = 0; mt < 4; ++mt)
        #pragma unroll
        for (int nt = 0; nt < 2; ++nt)
            #pragma unroll
            for (int i = 0; i < 4; ++i) {
                const int m = m0 + mw + mt * 16 + qd * 4 + i;
                const int n = n0 + nw + nt * 16 + ln;
                outF[(size_t)m * 1024 + n] = acc[mt][nt][i];
            }
}

// Flash attention, 4 waves x 32 q-rows (2 m-tiles), double-buffered K/V DMA.
// Grid (16,32) = (S/128, B*H), 256 threads. Row-sums via MFMA-with-ones (accL).
__global__ __launch_bounds__(256, 3)
void fattn(const unsigned short* __restrict__ Q, const unsigned short* __restrict__ Ksw,
           const unsigned short* __restrict__ Vsw, unsigned short* __restrict__ ctx) {
    __shared__ __align__(16) unsigned short Ks2[2][512 * 8];
    __shared__ __align__(16) unsigned short Vs2[2][512 * 8];
    __shared__ __align__(16) unsigned short Pw[4][32 * 72];

    const int t = threadIdx.x, lane = t & 63, w = t >> 6;
    const int ln = lane & 15, qd = lane >> 4;
    const int bh = blockIdx.y, m0 = blockIdx.x * 128;
    const size_t head = (size_t)bh * 2048 * 64;

    s16x8 qf[2][2];
    #pragma unroll
    for (int mt = 0; mt < 2; ++mt)
        #pragma unroll
        for (int kk = 0; kk < 2; ++kk)
            qf[mt][kk] = *(const s16x8*)(Q + head + (size_t)(m0 + w * 32 + mt * 16 + ln) * 64 + kk * 32 + qd * 8);

    s16x8 ones;
    #pragma unroll
    for (int j = 0; j < 8; ++j) ones[j] = (short)0x3F80;   // bf16 1.0

    f32x4v accO[2][4] = {};
    f32x4v accL[2] = {};
    unsigned short* pw = Pw[w];

    {   // prefetch kt=0 into buf 0
        const size_t tb = (size_t)bh * 32 * 512;
        #pragma unroll
        for (int j = 0; j < 2; ++j) {
            gld_lds16(Ksw + (tb + w * 128 + j * 64 + lane) * 8, &Ks2[0][(w * 128 + j * 64) * 8]);
            gld_lds16(Vsw + (tb + w * 128 + j * 64 + lane) * 8, &Vs2[0][(w * 128 + j * 64) * 8]);
        }
    }

    for (int kt = 0; kt < 32; ++kt) {
        const int cur = kt & 1;
        __syncthreads();   // buf[cur] DMA complete; prior-iter LDS reads done
        if (kt + 1 < 32) {
            const size_t tb = ((size_t)bh * 32 + kt + 1) * 512;
            #pragma unroll
            for (int j = 0; j < 2; ++j) {
                gld_lds16(Ksw + (tb + w * 128 + j * 64 + lane) * 8, &Ks2[cur ^ 1][(w * 128 + j * 64) * 8]);
                gld_lds16(Vsw + (tb + w * 128 + j * 64 + lane) * 8, &Vs2[cur ^ 1][(w * 128 + j * 64) * 8]);
            }
        }

        // S = Q K^T (pre-scaled by log2e); b-frag shared across both m-tiles
        f32x4v accS[2][4] = {};
        #pragma unroll
        for (int kk = 0; kk < 2; ++kk)
            #pragma unroll
            for (int nt = 0; nt < 4; ++nt) {
                s16x8 b = *(const s16x8*)&Ks2[cur][((kk * 4 + qd) * 64 + nt * 16 + ln) * 8];
                accS[0][nt] = __builtin_amdgcn_mfma_f32_16x16x32_bf16(qf[0][kk], b, accS[0][nt], 0, 0, 0);
                accS[1][nt] = __builtin_amdgcn_mfma_f32_16x16x32_bf16(qf[1][kk], b, accS[1][nt], 0, 0, 0);
            }

        // P = 2^S -> bf16 (packed cvt), spill C-layout -> A-layout
        #pragma unroll
        for (int mt = 0; mt < 2; ++mt)
            #pragma unroll
            for (int nt = 0; nt < 4; ++nt)
                #pragma unroll
                for (int i2 = 0; i2 < 2; ++i2) {
                    float p0 = exp2f(accS[mt][nt][2 * i2]);
                    float p1 = exp2f(accS[mt][nt][2 * i2 + 1]);
                    unsigned int pp = pkbf(p0, p1);
                    pw[(mt * 16 + qd * 4 + 2 * i2) * 72 + nt * 16 + ln]     = (unsigned short)(pp & 0xffffu);
                    pw[(mt * 16 + qd * 4 + 2 * i2 + 1) * 72 + nt * 16 + ln] = (unsigned short)(pp >> 16);
                }

        // O += P V ; L += P 1  (a-frags reused; b-frags shared across m-tiles)
        #pragma unroll
        for (int kk = 0; kk < 2; ++kk) {
            s16x8 a0 = *(const s16x8*)&pw[(0 + ln) * 72 + kk * 32 + qd * 8];
            s16x8 a1 = *(const s16x8*)&pw[(16 + ln) * 72 + kk * 32 + qd * 8];
            accL[0] = __builtin_amdgcn_mfma_f32_16x16x32_bf16(a0, ones, accL[0], 0, 0, 0);
            accL[1] = __builtin_amdgcn_mfma_f32_16x16x32_bf16(a1, ones, accL[1], 0, 0, 0);
            #pragma unroll
            for (int nt = 0; nt < 4; ++nt) {
                s16x8 b = *(const s16x8*)&Vs2[cur][((kk * 4 + qd) * 64 + nt * 16 + ln) * 8];
                accO[0][nt] = __builtin_amdgcn_mfma_f32_16x16x32_bf16(a0, b, accO[0][nt], 0, 0, 0);
                accO[1][nt] = __builtin_amdgcn_mfma_f32_16x16x32_bf16(a1, b, accO[1][nt], 0, 0, 0);
            }
        }
    }

    // accL[mt][i] = full row-sum (identical across columns) -> no shuffle needed
    // ctx in A/W swizzle: m = b*2048+s, k = h*64+d
    #pragma unroll
    for (int mt = 0; mt < 2; ++mt)
        #pragma unroll
        for (int i = 0; i < 4; ++i) {
            const float inv = 1.f / accL[mt][i];
            const int mrow = (bh >> 4) * 2048 + m0 + w * 32 + mt * 16 + qd * 4 + i;
            #pragma unroll
            for (int nt = 0; nt < 4; ++nt) {
                const int k = (bh & 15) * 64 + nt * 16 + ln;
                const size_t g = ((size_t)(mrow >> 7) * 128 + (k >> 3)) * 128 + (mrow & 127);
                ctx[g * 8 + (k & 7)] = f2bf(accO[mt][nt][i] * inv);
            }
        }
}

extern "C" void kernel_launch(void* const* d_in, const int* in_sizes, int n_in,
                              void* d_out, int out_size, void* d_ws, size_t ws_size,
                              hipStream_t stream) {
    char* ws = (char*)d_ws;
    unsigned short* Qb  = (unsigned short*)(ws);
    unsigned short* Ksw = (unsigned short*)(ws + ((size_t)8 << 20));
    unsigned short* Vsw = (unsigned short*)(ws + ((size_t)16 << 20));
    unsigned short* Wqt = (unsigned short*)(ws + ((size_t)24 << 20));
    unsigned short* Wkt = (unsigned short*)(ws + ((size_t)26 << 20));
    unsigned short* Wvt = (unsigned short*)(ws + ((size_t)28 << 20));
    unsigned short* ctx = (unsigned short*)(ws + ((size_t)24 << 20));  // after QKV GEMM
    unsigned short* Wot = (unsigned short*)(ws);                        // after fattn (Qb dead)

    cvt3<<<dim3(16, 16, 3), 256, 0, stream>>>((const float*)d_in[3], (const float*)d_in[4],
                                              (const float*)d_in[5], Wqt, Wkt, Wvt);

    gemm_qkv<<<dim3(8, 32, 3), 256, 0, stream>>>(
        (const float*)d_in[0], (const float*)d_in[1], (const float*)d_in[2],
        Wqt, Wkt, Wvt, Qb, Ksw, Vsw, 0.125f * 1.44269504f);

    fattn<<<dim3(16, 32), dim3(256), 0, stream>>>(Qb, Ksw, Vsw, ctx);

    cvt3<<<dim3(16, 16, 1), 256, 0, stream>>>((const float*)d_in[6], nullptr, nullptr,
                                              Wot, nullptr, nullptr);

    gemm_out<<<dim3(16, 32), 256, 0, stream>>>(ctx, Wot, (float*)d_out);
}